// Round 7
// baseline (444.256 us; speedup 1.0000x reference)
//
#include <hip/hip_runtime.h>

#define N_NODES 50000
#define N_EDGES 1600000
#define D_FEAT 32
#define SCAN_BLOCK 1024
#define N_SCAN_BLOCKS ((N_NODES + SCAN_BLOCK - 1) / SCAN_BLOCK)  // 49
#define NPART 8
#define PART_SIZE (N_NODES / NPART)      // 6250 exact
#define NSTRIPE 32
#define NQ (N_EDGES / 4)                 // 400000 quads
#define NQB (NQ / NSTRIPE)               // 12500 quads per stripe

// ws layout (int units):
//   bcnt  [0, 32N)        per-stripe per-node counts
//   offb  [32N, 64N)      per-stripe per-node base offsets
//   cnt   [64N, 65N)      per-node total count
//   excl  [65N, 66N)      per-block exclusive scan of cnt
//   off   [66N, 67N+1)    global exclusive offsets, off[N] = E
//   bsum  [67N+64, 67N+128)
//   bsumx [67N+128, 67N+192)
//   pair  [67N+192, 67N+192+2E)   int2 {e, src[e]} sorted by dst (12.8 MB)
#define WS_BCNT  0
#define WS_OFFB  (32 * N_NODES)
#define WS_CNT   (64 * N_NODES)
#define WS_EXCL  (65 * N_NODES)
#define WS_OFF   (66 * N_NODES)
#define WS_BSUM  (67 * N_NODES + 64)
#define WS_BSUMX (67 * N_NODES + 128)
#define WS_PAIR  (67 * N_NODES + 192)

typedef float f4 __attribute__((ext_vector_type(4)));

// -------- main path --------

// Partitioned LDS histogram: block (stripe ib, partition p=blockIdx&7) counts
// dsts in [p*PART_SIZE, +PART_SIZE) over quad-stripe [ib*NQB, +NQB).
// LDS atomics only (no global atomics, no rank array, no atomic returns on
// the critical path). blockIdx&7 keeps each partition's work XCD-local.
__global__ void hist_part(const int* __restrict__ dst, int* __restrict__ bcnt) {
    __shared__ int lh[PART_SIZE];
    int p = blockIdx.x & (NPART - 1);
    int ib = blockIdx.x >> 3;
    int lo = p * PART_SIZE;
    for (int k = threadIdx.x; k < PART_SIZE; k += blockDim.x) lh[k] = 0;
    __syncthreads();
    const int4* dq = (const int4*)dst;
    int q0 = ib * NQB;
    for (int q = q0 + threadIdx.x; q < q0 + NQB; q += blockDim.x) {
        int4 d4 = dq[q];
        if ((unsigned)(d4.x - lo) < (unsigned)PART_SIZE) atomicAdd(&lh[d4.x - lo], 1);
        if ((unsigned)(d4.y - lo) < (unsigned)PART_SIZE) atomicAdd(&lh[d4.y - lo], 1);
        if ((unsigned)(d4.z - lo) < (unsigned)PART_SIZE) atomicAdd(&lh[d4.z - lo], 1);
        if ((unsigned)(d4.w - lo) < (unsigned)PART_SIZE) atomicAdd(&lh[d4.w - lo], 1);
    }
    __syncthreads();
    for (int k = threadIdx.x; k < PART_SIZE; k += blockDim.x)
        bcnt[ib * N_NODES + lo + k] = lh[k];
}

// cnt[n] = sum over 32 stripes of bcnt[i][n]  (coalesced row passes)
__global__ void sum_bcnt(const int* __restrict__ bcnt, int* __restrict__ cnt) {
    int n = blockIdx.x * blockDim.x + threadIdx.x;
    if (n >= N_NODES) return;
    int s = 0;
#pragma unroll
    for (int i = 0; i < NSTRIPE; ++i) s += bcnt[i * N_NODES + n];
    cnt[n] = s;
}

__global__ void scan_blocks(const int* __restrict__ cnt,
                            int* __restrict__ excl,
                            int* __restrict__ bsum) {
    __shared__ int lds[SCAN_BLOCK];
    int tid = threadIdx.x;
    int i = blockIdx.x * SCAN_BLOCK + tid;
    int v = (i < N_NODES) ? cnt[i] : 0;
    int sum = v;
    lds[tid] = v;
    __syncthreads();
    for (int ofs = 1; ofs < SCAN_BLOCK; ofs <<= 1) {
        int t = (tid >= ofs) ? lds[tid - ofs] : 0;
        __syncthreads();
        sum += t;
        lds[tid] = sum;
        __syncthreads();
    }
    if (i < N_NODES) excl[i] = sum - v;
    if (tid == SCAN_BLOCK - 1) bsum[blockIdx.x] = lds[SCAN_BLOCK - 1];
}

// one wave: shuffle-based exclusive scan of the 49 block sums
__global__ void scan_bsums(const int* __restrict__ bsum, int* __restrict__ bsumx) {
    int lane = threadIdx.x;
    int orig = (lane < N_SCAN_BLOCKS) ? bsum[lane] : 0;
    int v = orig;
    for (int o = 1; o < 64; o <<= 1) {
        int t = __shfl_up(v, o);
        if (lane >= o) v += t;
    }
    if (lane < N_SCAN_BLOCKS) bsumx[lane] = v - orig;
}

// off[i] = global exclusive offset; off[N] = E sentinel
__global__ void finalize_off(const int* __restrict__ excl,
                             const int* __restrict__ bsumx,
                             int* __restrict__ off) {
    int i = blockIdx.x * SCAN_BLOCK + threadIdx.x;
    if (i < N_NODES) off[i] = excl[i] + bsumx[blockIdx.x];
    else if (i == N_NODES) off[i] = N_EDGES;
}

// offb[i][n] = off[n] + sum_{i'<i} bcnt[i'][n]  (per-stripe cursor bases;
// replaces the rank array — stable across stripes)
__global__ void block_bases(const int* __restrict__ off,
                            const int* __restrict__ bcnt,
                            int* __restrict__ offb) {
    int n = blockIdx.x * blockDim.x + threadIdx.x;
    if (n >= N_NODES) return;
    int run = off[n];
#pragma unroll
    for (int i = 0; i < NSTRIPE; ++i) {
        offb[i * N_NODES + n] = run;
        run += bcnt[i * N_NODES + n];
    }
}

// Partitioned scatter: same (partition, stripe) mapping as hist_part.
// Cursors live in LDS (init from offb, coalesced); slots claimed via LDS
// atomicAdd (fast, no global atomics). Partition p's pair slice (~1.6 MB)
// is written only by blocks with blockIdx%8==p (one XCD) -> 64B sectors
// merge in a single L2 before writeback.
__global__ void scatter_part(const int* __restrict__ src,
                             const int* __restrict__ dst,
                             const int* __restrict__ offb,
                             int2* __restrict__ pair) {
    __shared__ int cur[PART_SIZE];
    int p = blockIdx.x & (NPART - 1);
    int ib = blockIdx.x >> 3;
    int lo = p * PART_SIZE;
    for (int k = threadIdx.x; k < PART_SIZE; k += blockDim.x)
        cur[k] = offb[ib * N_NODES + lo + k];
    __syncthreads();
    const int4* dq = (const int4*)dst;
    const int4* sq = (const int4*)src;
    int q0 = ib * NQB;
    for (int q = q0 + threadIdx.x; q < q0 + NQB; q += blockDim.x) {
        int4 d4 = dq[q];
        bool ax = (unsigned)(d4.x - lo) < (unsigned)PART_SIZE;
        bool ay = (unsigned)(d4.y - lo) < (unsigned)PART_SIZE;
        bool az = (unsigned)(d4.z - lo) < (unsigned)PART_SIZE;
        bool aw = (unsigned)(d4.w - lo) < (unsigned)PART_SIZE;
        if (!(ax | ay | az | aw)) continue;
        int4 s4 = sq[q];
        int e0 = q * 4;
        if (ax) { int pos = atomicAdd(&cur[d4.x - lo], 1); pair[pos] = make_int2(e0,     s4.x); }
        if (ay) { int pos = atomicAdd(&cur[d4.y - lo], 1); pair[pos] = make_int2(e0 + 1, s4.y); }
        if (az) { int pos = atomicAdd(&cur[d4.z - lo], 1); pair[pos] = make_int2(e0 + 2, s4.z); }
        if (aw) { int pos = atomicAdd(&cur[d4.w - lo], 1); pair[pos] = make_int2(e0 + 3, s4.w); }
    }
}

// per (node, float4-group): walk the node's contiguous pair records, gather
// edge_feat/node_feat rows, relu-sum on the fly, add eps-scaled residual.
// 8-lane groups broadcast pair records via shfl; main loop fully unrolled.
// (R4-proven body; off/cnt materialized.)
__global__ void reduce_gather(const float* __restrict__ node_feat,
                              const float* __restrict__ edge_feat,
                              const float* __restrict__ eps,
                              const int* __restrict__ off,
                              const int* __restrict__ cnt,
                              const int2* __restrict__ pair,
                              float* __restrict__ out) {
    int t = blockIdx.x * blockDim.x + threadIdx.x;
    int n = t >> 3;
    int g = t & 7;
    if (n >= N_NODES) return;

    int start = off[n];
    int c = cnt[n];
    int gbase = (threadIdx.x & 63) & ~7;  // base lane of this 8-lane group

    const f4* efp = (const f4*)edge_feat;
    const f4* nfp = (const f4*)node_feat;

    f4 acc = (f4)(0.f);
    int i0 = 0;
    for (; i0 + 8 <= c; i0 += 8) {
        int2 p = pair[start + i0 + g];  // 8 lanes x 8B = 64B coalesced
#pragma unroll
        for (int j = 0; j < 8; ++j) {
            int e = __shfl(p.x, gbase + j);
            int s = __shfl(p.y, gbase + j);
            f4 ef = __builtin_nontemporal_load(&efp[(size_t)e * 8 + g]);
            f4 nf = nfp[(size_t)s * 8 + g];
            acc.x += fmaxf(nf.x + ef.x, 0.f);
            acc.y += fmaxf(nf.y + ef.y, 0.f);
            acc.z += fmaxf(nf.z + ef.z, 0.f);
            acc.w += fmaxf(nf.w + ef.w, 0.f);
        }
    }
    int rem = c - i0;
    if (rem > 0) {
        int2 p = (g < rem) ? pair[start + i0 + g] : make_int2(0, 0);
        for (int j = 0; j < rem; ++j) {
            int e = __shfl(p.x, gbase + j);
            int s = __shfl(p.y, gbase + j);
            f4 ef = __builtin_nontemporal_load(&efp[(size_t)e * 8 + g]);
            f4 nf = nfp[(size_t)s * 8 + g];
            acc.x += fmaxf(nf.x + ef.x, 0.f);
            acc.y += fmaxf(nf.y + ef.y, 0.f);
            acc.z += fmaxf(nf.z + ef.z, 0.f);
            acc.w += fmaxf(nf.w + ef.w, 0.f);
        }
    }

    float scale = 1.0f + eps[0];
    f4 h = nfp[(size_t)n * 8 + g];
    f4 o;
    o.x = scale * h.x + acc.x;
    o.y = scale * h.y + acc.y;
    o.z = scale * h.z + acc.z;
    o.w = scale * h.w + acc.w;
    ((f4*)out)[(size_t)n * 8 + g] = o;
}

// -------- fallback path (tiny ws): direct atomics --------

__global__ void fb_init_out(const float* __restrict__ node_feat,
                            const float* __restrict__ eps,
                            float* __restrict__ out) {
    int i = blockIdx.x * blockDim.x + threadIdx.x;
    const int n4 = N_NODES * D_FEAT / 4;
    float scale = 1.0f + eps[0];
    if (i < n4) {
        float4 v = ((const float4*)node_feat)[i];
        v.x *= scale; v.y *= scale; v.z *= scale; v.w *= scale;
        ((float4*)out)[i] = v;
    }
}

__global__ void fb_scatter(const float* __restrict__ node_feat,
                           const float* __restrict__ edge_feat,
                           const int* __restrict__ src,
                           const int* __restrict__ dst,
                           float* __restrict__ out) {
    int t = blockIdx.x * blockDim.x + threadIdx.x;
    int e = t >> 3;
    int g = t & 7;
    if (e >= N_EDGES) return;
    int s = src[e];
    int d = dst[e];
    float4 nf = ((const float4*)node_feat)[s * 8 + g];
    float4 ef = ((const float4*)edge_feat)[(size_t)e * 8 + g];
    float* op = out + (size_t)d * D_FEAT + g * 4;
    unsafeAtomicAdd(op + 0, fmaxf(nf.x + ef.x, 0.f));
    unsafeAtomicAdd(op + 1, fmaxf(nf.y + ef.y, 0.f));
    unsafeAtomicAdd(op + 2, fmaxf(nf.z + ef.z, 0.f));
    unsafeAtomicAdd(op + 3, fmaxf(nf.w + ef.w, 0.f));
}

extern "C" void kernel_launch(void* const* d_in, const int* in_sizes, int n_in,
                              void* d_out, int out_size, void* d_ws, size_t ws_size,
                              hipStream_t stream) {
    const float* node_feat = (const float*)d_in[0];
    const float* edge_feat = (const float*)d_in[1];
    const float* eps       = (const float*)d_in[2];
    const int*   src       = (const int*)d_in[3];
    const int*   dst       = (const int*)d_in[4];
    float* out = (float*)d_out;

    const int B = 256;
    const size_t need = ((size_t)WS_PAIR + 2ull * N_EDGES) * sizeof(int);

    if (ws_size < need) {
        // fallback: direct fp32 atomics (no ws)
        int n4 = N_NODES * D_FEAT / 4;
        fb_init_out<<<(n4 + B - 1) / B, B, 0, stream>>>(node_feat, eps, out);
        long long total = (long long)N_EDGES * 8;
        fb_scatter<<<(int)((total + B - 1) / B), B, 0, stream>>>(
            node_feat, edge_feat, src, dst, out);
        return;
    }

    int* ws = (int*)d_ws;
    int*  bcnt  = ws + WS_BCNT;
    int*  offb  = ws + WS_OFFB;
    int*  cnt   = ws + WS_CNT;
    int*  excl  = ws + WS_EXCL;
    int*  off   = ws + WS_OFF;
    int*  bsum  = ws + WS_BSUM;
    int*  bsumx = ws + WS_BSUMX;
    int2* pair  = (int2*)(ws + WS_PAIR);

    hist_part<<<NPART * NSTRIPE, B, 0, stream>>>(dst, bcnt);
    sum_bcnt<<<(N_NODES + B - 1) / B, B, 0, stream>>>(bcnt, cnt);
    scan_blocks<<<N_SCAN_BLOCKS, SCAN_BLOCK, 0, stream>>>(cnt, excl, bsum);
    scan_bsums<<<1, 64, 0, stream>>>(bsum, bsumx);
    finalize_off<<<N_SCAN_BLOCKS, SCAN_BLOCK, 0, stream>>>(excl, bsumx, off);
    block_bases<<<(N_NODES + B - 1) / B, B, 0, stream>>>(off, bcnt, offb);

    scatter_part<<<NPART * NSTRIPE, B, 0, stream>>>(src, dst, offb, pair);

    long long ntotal = (long long)N_NODES * 8;
    reduce_gather<<<(int)((ntotal + B - 1) / B), B, 0, stream>>>(
        node_feat, edge_feat, eps, off, cnt, pair, out);
}

// Round 9
// 433.081 us; speedup vs baseline: 1.0258x; 1.0258x over previous
//
#include <hip/hip_runtime.h>

#define N_NODES 50000
#define N_EDGES 1600000
#define D_FEAT 32
#define SCAN_BLOCK 1024
#define N_SCAN_BLOCKS ((N_NODES + SCAN_BLOCK - 1) / SCAN_BLOCK)  // 49

// ws layout (int units):
//   cnt   [0, N)          per-dst edge count (histogram)
//   excl  [N, 2N)         per-block exclusive scan of cnt
//   bsum  [2N, 2N+64)
//   bsumx [2N+64, 2N+128)
//   rank  [2N+128, 2N+128+E)       rank of edge within its dst bin
//   pair  [2N+128+E, 2N+128+3E)    int2 {e, src[e]} sorted by dst (12.8 MB)
#define WS_CNT   0
#define WS_EXCL  (N_NODES)
#define WS_BSUM  (2 * N_NODES)
#define WS_BSUMX (2 * N_NODES + 64)
#define WS_RANK  (2 * N_NODES + 128)
#define WS_PAIR  (2 * N_NODES + 128 + N_EDGES)

typedef float f4 __attribute__((ext_vector_type(4)));
typedef int   i2 __attribute__((ext_vector_type(2)));

// -------- main path --------

// rank[e] = old count of dst[e]; cnt accumulates histogram.
// 8 edges/thread (2x int4): half the waves of the 4-edge version, 8
// outstanding atomic-returns per thread to hide cross-XCD atomic latency.
__global__ void hist_rank(const int* __restrict__ dst,
                          int* __restrict__ cnt,
                          int* __restrict__ rank) {
    int q = blockIdx.x * blockDim.x + threadIdx.x;
    const int NO = N_EDGES / 8;
    if (q >= NO) return;
    int4 da = ((const int4*)dst)[q * 2];
    int4 db = ((const int4*)dst)[q * 2 + 1];
    int4 ra, rb;
    ra.x = atomicAdd(&cnt[da.x], 1);
    ra.y = atomicAdd(&cnt[da.y], 1);
    ra.z = atomicAdd(&cnt[da.z], 1);
    ra.w = atomicAdd(&cnt[da.w], 1);
    rb.x = atomicAdd(&cnt[db.x], 1);
    rb.y = atomicAdd(&cnt[db.y], 1);
    rb.z = atomicAdd(&cnt[db.z], 1);
    rb.w = atomicAdd(&cnt[db.w], 1);
    ((int4*)rank)[q * 2]     = ra;
    ((int4*)rank)[q * 2 + 1] = rb;
}

__global__ void scan_blocks(const int* __restrict__ cnt,
                            int* __restrict__ excl,
                            int* __restrict__ bsum) {
    __shared__ int lds[SCAN_BLOCK];
    int tid = threadIdx.x;
    int i = blockIdx.x * SCAN_BLOCK + tid;
    int v = (i < N_NODES) ? cnt[i] : 0;
    int sum = v;
    lds[tid] = v;
    __syncthreads();
    for (int ofs = 1; ofs < SCAN_BLOCK; ofs <<= 1) {
        int t = (tid >= ofs) ? lds[tid - ofs] : 0;
        __syncthreads();
        sum += t;
        lds[tid] = sum;
        __syncthreads();
    }
    if (i < N_NODES) excl[i] = sum - v;
    if (tid == SCAN_BLOCK - 1) bsum[blockIdx.x] = lds[SCAN_BLOCK - 1];
}

// one wave: shuffle-based exclusive scan of the 49 block sums
__global__ void scan_bsums(const int* __restrict__ bsum, int* __restrict__ bsumx) {
    int lane = threadIdx.x;
    int orig = (lane < N_SCAN_BLOCKS) ? bsum[lane] : 0;
    int v = orig;
    for (int o = 1; o < 64; o <<= 1) {
        int t = __shfl_up(v, o);
        if (lane >= o) v += t;
    }
    if (lane < N_SCAN_BLOCKS) bsumx[lane] = v - orig;
}

// R4-proven scatter (unchanged): rank-based, atomic-free store path,
// 4 edges/thread, int4 reads, off computed inline.
__global__ void scatter_pairs(const int* __restrict__ src,
                              const int* __restrict__ dst,
                              const int* __restrict__ excl,
                              const int* __restrict__ bsumx,
                              const int* __restrict__ rank,
                              int2* __restrict__ pair) {
    int q = blockIdx.x * blockDim.x + threadIdx.x;
    const int NQ = N_EDGES / 4;
    if (q >= NQ) return;
    int4 d4 = ((const int4*)dst)[q];
    int4 s4 = ((const int4*)src)[q];
    int4 r4 = ((const int4*)rank)[q];
    int e0 = q * 4;
    pair[excl[d4.x] + bsumx[d4.x >> 10] + r4.x] = make_int2(e0,     s4.x);
    pair[excl[d4.y] + bsumx[d4.y >> 10] + r4.y] = make_int2(e0 + 1, s4.y);
    pair[excl[d4.z] + bsumx[d4.z >> 10] + r4.z] = make_int2(e0 + 2, s4.z);
    pair[excl[d4.w] + bsumx[d4.w >> 10] + r4.w] = make_int2(e0 + 3, s4.w);
}

// per (node, float4-group): walk the node's contiguous pair records, gather
// edge_feat/node_feat rows, relu-sum on the fly, add eps-scaled residual.
// 16-edge main loop: two nontemporal pair loads issued back-to-back ->
// 16 independent edge-row gathers in flight per group (double the MLP of
// the 8-edge version; the random 128B gather latency is the limiter).
__global__ void reduce_gather(const float* __restrict__ node_feat,
                              const float* __restrict__ edge_feat,
                              const float* __restrict__ eps,
                              const int* __restrict__ excl,
                              const int* __restrict__ bsumx,
                              const int* __restrict__ cnt,
                              const int* __restrict__ pair,  // int2 records, viewed as 2x int
                              float* __restrict__ out) {
    int t = blockIdx.x * blockDim.x + threadIdx.x;
    int n = t >> 3;
    int g = t & 7;
    if (n >= N_NODES) return;

    int start = excl[n] + bsumx[n >> 10];
    int c = cnt[n];
    int gbase = (threadIdx.x & 63) & ~7;  // base lane of this 8-lane group

    const f4* efp = (const f4*)edge_feat;
    const f4* nfp = (const f4*)node_feat;
    const i2* pp  = (const i2*)pair;

    f4 acc = (f4)(0.f);
    int i0 = 0;
    for (; i0 + 16 <= c; i0 += 16) {
        i2 pa = __builtin_nontemporal_load(&pp[start + i0 + g]);
        i2 pb = __builtin_nontemporal_load(&pp[start + i0 + 8 + g]);
#pragma unroll
        for (int j = 0; j < 8; ++j) {
            int e = __shfl(pa.x, gbase + j);
            int s = __shfl(pa.y, gbase + j);
            f4 ef = __builtin_nontemporal_load(&efp[(size_t)e * 8 + g]);
            f4 nf = nfp[(size_t)s * 8 + g];
            acc.x += fmaxf(nf.x + ef.x, 0.f);
            acc.y += fmaxf(nf.y + ef.y, 0.f);
            acc.z += fmaxf(nf.z + ef.z, 0.f);
            acc.w += fmaxf(nf.w + ef.w, 0.f);
        }
#pragma unroll
        for (int j = 0; j < 8; ++j) {
            int e = __shfl(pb.x, gbase + j);
            int s = __shfl(pb.y, gbase + j);
            f4 ef = __builtin_nontemporal_load(&efp[(size_t)e * 8 + g]);
            f4 nf = nfp[(size_t)s * 8 + g];
            acc.x += fmaxf(nf.x + ef.x, 0.f);
            acc.y += fmaxf(nf.y + ef.y, 0.f);
            acc.z += fmaxf(nf.z + ef.z, 0.f);
            acc.w += fmaxf(nf.w + ef.w, 0.f);
        }
    }
    if (i0 + 8 <= c) {
        i2 p = __builtin_nontemporal_load(&pp[start + i0 + g]);
#pragma unroll
        for (int j = 0; j < 8; ++j) {
            int e = __shfl(p.x, gbase + j);
            int s = __shfl(p.y, gbase + j);
            f4 ef = __builtin_nontemporal_load(&efp[(size_t)e * 8 + g]);
            f4 nf = nfp[(size_t)s * 8 + g];
            acc.x += fmaxf(nf.x + ef.x, 0.f);
            acc.y += fmaxf(nf.y + ef.y, 0.f);
            acc.z += fmaxf(nf.z + ef.z, 0.f);
            acc.w += fmaxf(nf.w + ef.w, 0.f);
        }
        i0 += 8;
    }
    int rem = c - i0;
    if (rem > 0) {
        i2 p = (i2)(0);
        if (g < rem) p = pp[start + i0 + g];
        for (int j = 0; j < rem; ++j) {
            int e = __shfl(p.x, gbase + j);
            int s = __shfl(p.y, gbase + j);
            f4 ef = __builtin_nontemporal_load(&efp[(size_t)e * 8 + g]);
            f4 nf = nfp[(size_t)s * 8 + g];
            acc.x += fmaxf(nf.x + ef.x, 0.f);
            acc.y += fmaxf(nf.y + ef.y, 0.f);
            acc.z += fmaxf(nf.z + ef.z, 0.f);
            acc.w += fmaxf(nf.w + ef.w, 0.f);
        }
    }

    float scale = 1.0f + eps[0];
    f4 h = nfp[(size_t)n * 8 + g];
    f4 o;
    o.x = scale * h.x + acc.x;
    o.y = scale * h.y + acc.y;
    o.z = scale * h.z + acc.z;
    o.w = scale * h.w + acc.w;
    ((f4*)out)[(size_t)n * 8 + g] = o;
}

// -------- fallback path (tiny ws): direct atomics --------

__global__ void fb_init_out(const float* __restrict__ node_feat,
                            const float* __restrict__ eps,
                            float* __restrict__ out) {
    int i = blockIdx.x * blockDim.x + threadIdx.x;
    const int n4 = N_NODES * D_FEAT / 4;
    float scale = 1.0f + eps[0];
    if (i < n4) {
        float4 v = ((const float4*)node_feat)[i];
        v.x *= scale; v.y *= scale; v.z *= scale; v.w *= scale;
        ((float4*)out)[i] = v;
    }
}

__global__ void fb_scatter(const float* __restrict__ node_feat,
                           const float* __restrict__ edge_feat,
                           const int* __restrict__ src,
                           const int* __restrict__ dst,
                           float* __restrict__ out) {
    int t = blockIdx.x * blockDim.x + threadIdx.x;
    int e = t >> 3;
    int g = t & 7;
    if (e >= N_EDGES) return;
    int s = src[e];
    int d = dst[e];
    float4 nf = ((const float4*)node_feat)[s * 8 + g];
    float4 ef = ((const float4*)edge_feat)[(size_t)e * 8 + g];
    float* op = out + (size_t)d * D_FEAT + g * 4;
    unsafeAtomicAdd(op + 0, fmaxf(nf.x + ef.x, 0.f));
    unsafeAtomicAdd(op + 1, fmaxf(nf.y + ef.y, 0.f));
    unsafeAtomicAdd(op + 2, fmaxf(nf.z + ef.z, 0.f));
    unsafeAtomicAdd(op + 3, fmaxf(nf.w + ef.w, 0.f));
}

extern "C" void kernel_launch(void* const* d_in, const int* in_sizes, int n_in,
                              void* d_out, int out_size, void* d_ws, size_t ws_size,
                              hipStream_t stream) {
    const float* node_feat = (const float*)d_in[0];
    const float* edge_feat = (const float*)d_in[1];
    const float* eps       = (const float*)d_in[2];
    const int*   src       = (const int*)d_in[3];
    const int*   dst       = (const int*)d_in[4];
    float* out = (float*)d_out;

    const int B = 256;
    const size_t need = ((size_t)WS_PAIR + 2ull * N_EDGES) * sizeof(int);

    if (ws_size < need) {
        // fallback: direct fp32 atomics (no ws)
        int n4 = N_NODES * D_FEAT / 4;
        fb_init_out<<<(n4 + B - 1) / B, B, 0, stream>>>(node_feat, eps, out);
        long long total = (long long)N_EDGES * 8;
        fb_scatter<<<(int)((total + B - 1) / B), B, 0, stream>>>(
            node_feat, edge_feat, src, dst, out);
        return;
    }

    int* ws = (int*)d_ws;
    int*  cnt   = ws + WS_CNT;
    int*  excl  = ws + WS_EXCL;
    int*  bsum  = ws + WS_BSUM;
    int*  bsumx = ws + WS_BSUMX;
    int*  rank  = ws + WS_RANK;
    int2* pair  = (int2*)(ws + WS_PAIR);

    hipMemsetAsync(cnt, 0, N_NODES * sizeof(int), stream);

    int no = N_EDGES / 8;
    hist_rank<<<(no + B - 1) / B, B, 0, stream>>>(dst, cnt, rank);
    scan_blocks<<<N_SCAN_BLOCKS, SCAN_BLOCK, 0, stream>>>(cnt, excl, bsum);
    scan_bsums<<<1, 64, 0, stream>>>(bsum, bsumx);

    int nq = N_EDGES / 4;
    scatter_pairs<<<(nq + B - 1) / B, B, 0, stream>>>(
        src, dst, excl, bsumx, rank, pair);

    long long ntotal = (long long)N_NODES * 8;
    reduce_gather<<<(int)((ntotal + B - 1) / B), B, 0, stream>>>(
        node_feat, edge_feat, eps, excl, bsumx, cnt, (const int*)pair, out);
}